// Round 2
// baseline (155.234 us; speedup 1.0000x reference)
//
#include <hip/hip_runtime.h>
#include <math.h>

#define NB 2
#define NO 512
#define NQ 512
#define OUT_DIM 128
#define LPAD 516   // logits row pitch (floats): 16B-aligned, bank-staggered

typedef __attribute__((ext_vector_type(8))) _Float16 half8;  // 4 VGPR
typedef __attribute__((ext_vector_type(4))) _Float16 half4;  // 2 VGPR
typedef __attribute__((ext_vector_type(4))) float f32x4;     // MFMA acc

__device__ __forceinline__ float softplus_f(float x) {
  return x > 0.0f ? x + log1pf(expf(-x)) : log1pf(expf(x));
}
// 2 f32 -> packed 2 f16 (RTZ) in one instruction
__device__ __forceinline__ int cvt2h(float x, float y) {
  return __builtin_bit_cast(int, __builtin_amdgcn_cvt_pkrtz(x, y));
}

// ---------------------------------------------------------------------------
// Prep: blocks 0..255 fused 2-layer MLP -> VT/VT2 (f16, head-transposed);
//       blocks 256..511 AO (f16).
__global__ __launch_bounds__(1024) void prep_kernel(
    const float* __restrict__ h_obs, const float* __restrict__ fw1,
    const float* __restrict__ fb1, const float* __restrict__ fw2,
    const float* __restrict__ fb2, const float* __restrict__ pos_obs,
    const float* __restrict__ kw1,
    _Float16* __restrict__ VT,    // [b][h][d][o] f16   (2*8*32*512)
    _Float16* __restrict__ VT2,   // same, squared values
    _Float16* __restrict__ AO_h)  // (B*NO, 256) f16
{
  if (blockIdx.x < 256) {
    __shared__ float s_red[4][4][256];
    __shared__ float s_hid[4][256];
    const int n  = threadIdx.x & 255;
    const int ks = threadIdx.x >> 8;
    const int r0 = blockIdx.x * 4;
    const int k0 = ks * 64;
    float a0 = 0.f, a1 = 0.f, a2 = 0.f, a3 = 0.f;
    #pragma unroll 8
    for (int kk = 0; kk < 64; ++kk) {
      int k = k0 + kk;
      float w = fw1[k * 256 + n];
      a0 = fmaf(h_obs[(r0 + 0) * 256 + k], w, a0);
      a1 = fmaf(h_obs[(r0 + 1) * 256 + k], w, a1);
      a2 = fmaf(h_obs[(r0 + 2) * 256 + k], w, a2);
      a3 = fmaf(h_obs[(r0 + 3) * 256 + k], w, a3);
    }
    s_red[ks][0][n] = a0; s_red[ks][1][n] = a1;
    s_red[ks][2][n] = a2; s_red[ks][3][n] = a3;
    __syncthreads();
    if (ks == 0) {
      float bb = fb1[n];
      #pragma unroll
      for (int r = 0; r < 4; ++r) {
        float v = s_red[0][r][n] + s_red[1][r][n] + s_red[2][r][n] + s_red[3][r][n] + bb;
        s_hid[r][n] = fmaxf(v, 0.f);
      }
    }
    __syncthreads();
    float c0 = 0.f, c1 = 0.f, c2 = 0.f, c3 = 0.f;
    #pragma unroll 8
    for (int kk = 0; kk < 64; ++kk) {
      int k = k0 + kk;
      float w = fw2[k * 256 + n];
      c0 = fmaf(s_hid[0][k], w, c0);
      c1 = fmaf(s_hid[1][k], w, c1);
      c2 = fmaf(s_hid[2][k], w, c2);
      c3 = fmaf(s_hid[3][k], w, c3);
    }
    __syncthreads();
    s_red[ks][0][n] = c0; s_red[ks][1][n] = c1;
    s_red[ks][2][n] = c2; s_red[ks][3][n] = c3;
    __syncthreads();
    if (ks == 0) {
      float bb = fb2[n];
      float vr[4];
      #pragma unroll
      for (int r = 0; r < 4; ++r)
        vr[r] = s_red[0][r][n] + s_red[1][r][n] + s_red[2][r][n] + s_red[3][r][n] + bb;
      // transpose store: thread n owns column (h,d); 4 consecutive o
      const int h  = n >> 5, d = n & 31;
      const int bb_ = r0 >> 9, o0 = r0 & 511;
      half4 pv, pv2;
      #pragma unroll
      for (int r = 0; r < 4; ++r) {
        pv[r]  = (_Float16)vr[r];
        pv2[r] = (_Float16)(vr[r] * vr[r]);
      }
      const size_t idx = ((size_t)((bb_ * 8 + h) * 32 + d)) * 512 + o0;
      *(half4*)(VT  + idx) = pv;
      *(half4*)(VT2 + idx) = pv2;
    }
  } else {
    const int i  = blockIdx.x - 256;
    const int b  = i >> 7;
    const int og = i & 127;
    const int ol = threadIdx.x >> 8;
    const int j  = threadIdx.x & 255;
    const int o  = og * 4 + ol;
    float c0 = kw1[3 * 256 + j] - kw1[6 * 256 + j];
    float c1 = kw1[4 * 256 + j] - kw1[7 * 256 + j];
    float c2 = kw1[5 * 256 + j] - kw1[8 * 256 + j];
    const float* p = pos_obs + ((size_t)(b * NO + o)) * 3;
    AO_h[(size_t)(b * NO + o) * 256 + j] =
        (_Float16)(fmaf(p[0], c0, fmaf(p[1], c1, p[2] * c2)));
  }
}

// ---------------------------------------------------------------------------
// Fused attention + out_proj. QT=2 per block, 512 threads (8 waves).
// Phase 1: f16 MFMA delta; A = relu(aq+ao) entirely in packed f16
//          (v_pk_add_f16 + v_pk_max_f16, zero unpack/cvt).
// Phase 2+3 merged per wave (=head): softmax rows in-wave, then PV and
//          P*V^2 as f16 MFMAs against pre-transposed VT / VT2.
__global__ __launch_bounds__(512, 4) void attn_fused(
    const _Float16* __restrict__ VT,    // [b][h][d][o]
    const _Float16* __restrict__ VT2,
    const _Float16* __restrict__ AO_h,  // (B*NO, 256) f16
    const float* __restrict__ kw1,       // (9, 256)
    const float* __restrict__ kb1,       // (256)
    const float* __restrict__ kw2,       // (256, 8)
    const float* __restrict__ kb2,       // (8)
    const float* __restrict__ log_sigma, // (8)
    const float* __restrict__ pos_obs,   // (B*NO, 3)
    const float* __restrict__ pos_query, // (B*NQ, 3)
    const float* __restrict__ ow, const float* __restrict__ obias,
    const float* __restrict__ vw, const float* __restrict__ vbias,
    float* __restrict__ out)
{
  __shared__ __align__(16) float s_logits[2][8 * LPAD];   // 33024 B
  __shared__ half8 s_Bh[512];                             // 8192 B (kw2 f16)
  __shared__ __align__(16) float s_pool[2048];            // 8192 B

  _Float16* s_aq2 = (_Float16*)s_pool;   // [2][256] f16 (phase 1 only)
  float*    s_hv  = s_pool;              // [(q*2+kind)*256+hd] (phase 3/4)
  float*    s_pred = s_pool + 1024;      // [ks][mode][q][128]  (phase 4)

  const int t   = threadIdx.x;
  const int bq0 = blockIdx.x * 2;
  const int b   = bq0 >> 9;

  // ---- prologue -----------------------------------------------------------
  float pqx[2], pqy[2], pqz[2];
  #pragma unroll
  for (int q = 0; q < 2; ++q) {
    pqx[q] = pos_query[(bq0 + q) * 3 + 0];
    pqy[q] = pos_query[(bq0 + q) * 3 + 1];
    pqz[q] = pos_query[(bq0 + q) * 3 + 2];
  }
  // aq[q][j] in f16
  {
    const int q = t >> 8, j = t & 255;
    float c0 = kw1[0 * 256 + j] + kw1[6 * 256 + j];
    float c1 = kw1[1 * 256 + j] + kw1[7 * 256 + j];
    float c2 = kw1[2 * 256 + j] + kw1[8 * 256 + j];
    s_aq2[q * 256 + j] = (_Float16)
        fmaf(pqx[q], c0, fmaf(pqy[q], c1, fmaf(pqz[q], c2, kb1[j])));
  }
  // logits prefill: rbf + kb2 for o = t, both q, all h
  {
    const int o = t;
    const float* p = pos_obs + (size_t)(b * NO + o) * 3;
    float px = p[0], py = p[1], pz = p[2];
    float d2q[2];
    #pragma unroll
    for (int q = 0; q < 2; ++q) {
      float r0 = pqx[q] - px, r1 = pqy[q] - py, r2 = pqz[q] - pz;
      d2q[q] = r0 * r0 + r1 * r1 + r2 * r2;
    }
    #pragma unroll
    for (int h = 0; h < 8; ++h) {
      float sg  = __expf(log_sigma[h]);
      float inv = 1.0f / (sg * sg + 1e-6f);
      float kbv = kb2[h];
      s_logits[0][h * LPAD + o] = __logf(__expf(-d2q[0] * inv) + 1e-8f) + kbv;
      s_logits[1][h * LPAD + o] = __logf(__expf(-d2q[1] * inv) + 1e-8f) + kbv;
    }
  }
  // B fragments: kw2 as f16
  {
    const int kstep = t >> 6, lane = t & 63;
    const int nh = lane & 15;
    const int kb_ = kstep * 32 + ((lane >> 4) & 3) * 8;
    half8 b8;
    #pragma unroll
    for (int i = 0; i < 8; ++i) {
      float v = (nh < 8) ? kw2[(kb_ + i) * 8 + nh] : 0.f;
      b8[i] = (_Float16)v;
    }
    s_Bh[kstep * 64 + lane] = b8;
  }
  __syncthreads();

  // ---- phase 1: f16 MFMA delta, A-build in packed f16 ---------------------
  {
    const int wave = t >> 6, lane = t & 63;
    const int quad = lane >> 4, mrow = lane & 15;
    const int tb   = wave * 4;                   // 4 o-tiles per wave, both q
    f32x4 C[2][4];
    #pragma unroll
    for (int q = 0; q < 2; ++q)
      #pragma unroll
      for (int jt = 0; jt < 4; ++jt) C[q][jt] = (f32x4){0.f, 0.f, 0.f, 0.f};

    const half8 z8 = {0, 0, 0, 0, 0, 0, 0, 0};
    for (int kstep = 0; kstep < 8; ++kstep) {
      const int koff = kstep * 32 + quad * 8;
      half8 aq0 = *(const half8*)(s_aq2 + koff);
      half8 aq1 = *(const half8*)(s_aq2 + 256 + koff);
      half8 bh  = s_Bh[kstep * 64 + lane];
      #pragma unroll
      for (int jt = 0; jt < 4; ++jt) {
        const int o = (tb + jt) * 16 + mrow;
        half8 ao = *(const half8*)(AO_h + ((size_t)(b * NO + o) << 8) + koff);
        half8 a0 = __builtin_elementwise_max(aq0 + ao, z8);   // pk_add + pk_max
        half8 a1 = __builtin_elementwise_max(aq1 + ao, z8);
        C[0][jt] = __builtin_amdgcn_mfma_f32_16x16x32_f16(a0, bh, C[0][jt], 0, 0, 0);
        C[1][jt] = __builtin_amdgcn_mfma_f32_16x16x32_f16(a1, bh, C[1][jt], 0, 0, 0);
      }
    }
    // epilogue: D[n=h=lane&15][m=quad*4+r]; add delta into prefilled logits
    const int hh = lane & 15;
    if (hh < 8) {
      #pragma unroll
      for (int q = 0; q < 2; ++q)
        #pragma unroll
        for (int jt = 0; jt < 4; ++jt) {
          const int ob2 = (tb + jt) * 16 + quad * 4;
          #pragma unroll
          for (int r = 0; r < 4; ++r)
            s_logits[q][hh * LPAD + ob2 + r] += C[q][jt][r];
        }
    }
  }
  __syncthreads();

  // ---- phase 2+3: per-wave (=head) softmax, then PV / PV^2 via MFMA -------
  {
    const int h = t >> 6, lane = t & 63;
    float invq[2];
    #pragma unroll
    for (int q = 0; q < 2; ++q) {
      float* pl = &s_logits[q][h * LPAD];
      float l8[8];
      float m = -1e30f;
      #pragma unroll
      for (int k = 0; k < 8; ++k) {
        l8[k] = pl[k * 64 + lane];
        m = fmaxf(m, l8[k]);
      }
      #pragma unroll
      for (int off = 32; off >= 1; off >>= 1) m = fmaxf(m, __shfl_xor(m, off, 64));
      float s = 0.f;
      #pragma unroll
      for (int k = 0; k < 8; ++k) {
        float p = __expf(l8[k] - m);
        pl[k * 64 + lane] = p;
        s += p;
      }
      #pragma unroll
      for (int off = 32; off >= 1; off >>= 1) s += __shfl_xor(s, off, 64);
      invq[q] = 1.0f / s;
    }
    // MFMA: A = VT/VT2 [m=d(16), k=o(32)], B = P [k=o, n=q], C[d, q].
    // Lane: dl = m-row (A), nq = n-col (B), kg*8 = k-range — same bits.
    const int nq = lane & 15, kg = lane >> 4, dl = lane & 15;
    const size_t vbase = ((size_t)(b * 8 + h) * 32 + dl) * 512;
    const _Float16* vt1 = VT  + vbase;
    const _Float16* vt2 = VT2 + vbase;
    const float* P = &s_logits[nq & 1][h * LPAD];  // cols>=2: dup of q0/q1, never read
    f32x4 Cm0 = {0.f,0.f,0.f,0.f}, Cm1 = Cm0, Cv0 = Cm0, Cv1 = Cm0;
    #pragma unroll 4
    for (int ks = 0; ks < 16; ++ks) {
      const int ob = ks * 32 + kg * 8;
      float4 p0 = *(const float4*)(P + ob);
      float4 p1 = *(const float4*)(P + ob + 4);
      int4 bi;
      bi.x = cvt2h(p0.x, p0.y); bi.y = cvt2h(p0.z, p0.w);
      bi.z = cvt2h(p1.x, p1.y); bi.w = cvt2h(p1.z, p1.w);
      half8 bh = __builtin_bit_cast(half8, bi);
      half8 am0 = *(const half8*)(vt1 + ob);
      half8 am1 = *(const half8*)(vt1 + 8192 + ob);   // d + 16
      half8 av0 = *(const half8*)(vt2 + ob);
      half8 av1 = *(const half8*)(vt2 + 8192 + ob);
      Cm0 = __builtin_amdgcn_mfma_f32_16x16x32_f16(am0, bh, Cm0, 0, 0, 0);
      Cm1 = __builtin_amdgcn_mfma_f32_16x16x32_f16(am1, bh, Cm1, 0, 0, 0);
      Cv0 = __builtin_amdgcn_mfma_f32_16x16x32_f16(av0, bh, Cv0, 0, 0, 0);
      Cv1 = __builtin_amdgcn_mfma_f32_16x16x32_f16(av1, bh, Cv1, 0, 0, 0);
    }
    // epilogue: C row = kg*4+r (=d_local), col = nq (=q). Normalize + var.
    if (nq < 2) {
      const float iv = nq ? invq[1] : invq[0];
      const int dbase = h * 32 + kg * 4;
      f32x4 m0, v0, m1, v1;
      #pragma unroll
      for (int r = 0; r < 4; ++r) {
        float a = Cm0[r] * iv;
        m0[r] = a; v0[r] = fmaxf(Cv0[r] * iv - a * a, 0.f);
        float c = Cm1[r] * iv;
        m1[r] = c; v1[r] = fmaxf(Cv1[r] * iv - c * c, 0.f);
      }
      *(f32x4*)(s_hv + (nq * 2 + 0) * 256 + dbase)      = m0;
      *(f32x4*)(s_hv + (nq * 2 + 1) * 256 + dbase)      = v0;
      *(f32x4*)(s_hv + (nq * 2 + 0) * 256 + dbase + 16) = m1;
      *(f32x4*)(s_hv + (nq * 2 + 1) * 256 + dbase + 16) = v1;
    }
  }
  __syncthreads();

  // ---- phase 4: out_proj, k-split 2, W read once per (mode,ks) ------------
  {
    const int ks = t >> 8, mode = (t >> 7) & 1, n = t & 127;
    const float* W  = mode ? vw : ow;
    const float* X0 = s_hv + mode * 256;        // q0
    const float* X1 = s_hv + (2 + mode) * 256;  // q1
    float a0 = 0.f, a1 = 0.f;
    const int k0 = ks * 128;
    #pragma unroll 4
    for (int k = k0; k < k0 + 128; k += 4) {
      float4 x0 = *(const float4*)&X0[k];
      float4 x1 = *(const float4*)&X1[k];
      float w0 = W[(k + 0) * 128 + n];
      float w1 = W[(k + 1) * 128 + n];
      float w2 = W[(k + 2) * 128 + n];
      float w3 = W[(k + 3) * 128 + n];
      a0 = fmaf(x0.x, w0, a0); a1 = fmaf(x1.x, w0, a1);
      a0 = fmaf(x0.y, w1, a0); a1 = fmaf(x1.y, w1, a1);
      a0 = fmaf(x0.z, w2, a0); a1 = fmaf(x1.z, w2, a1);
      a0 = fmaf(x0.w, w3, a0); a1 = fmaf(x1.w, w3, a1);
    }
    s_pred[((ks * 2 + mode) * 2 + 0) * 128 + n] = a0;   // s_pred disjoint from s_hv
    s_pred[((ks * 2 + mode) * 2 + 1) * 128 + n] = a1;
  }
  __syncthreads();
  {
    const int q = t >> 8, mode = (t >> 7) & 1, n = t & 127;
    float v = s_pred[((0 * 2 + mode) * 2 + q) * 128 + n]
            + s_pred[((1 * 2 + mode) * 2 + q) * 128 + n]
            + (mode ? vbias[n] : obias[n]);
    if (mode) v = softplus_f(v);
    out[(size_t)mode * (NB * NQ * OUT_DIM) + (size_t)(bq0 + q) * OUT_DIM + n] = v;
  }
}

// ---------------------------------------------------------------------------
extern "C" void kernel_launch(void* const* d_in, const int* in_sizes, int n_in,
                              void* d_out, int out_size, void* d_ws, size_t ws_size,
                              hipStream_t stream)
{
  const float* h_obs     = (const float*)d_in[0];
  const float* pos_obs   = (const float*)d_in[1];
  const float* pos_query = (const float*)d_in[2];
  const float* fw1       = (const float*)d_in[3];
  const float* fb1       = (const float*)d_in[4];
  const float* fw2       = (const float*)d_in[5];
  const float* fb2       = (const float*)d_in[6];
  const float* log_sigma = (const float*)d_in[7];
  const float* kw1       = (const float*)d_in[8];
  const float* kb1       = (const float*)d_in[9];
  const float* kw2       = (const float*)d_in[10];
  const float* kb2       = (const float*)d_in[11];
  const float* ow        = (const float*)d_in[12];
  const float* ob        = (const float*)d_in[13];
  const float* vw        = (const float*)d_in[14];
  const float* vb        = (const float*)d_in[15];

  float* out = (float*)d_out;
  _Float16* ws = (_Float16*)d_ws;

  _Float16* AO_h = ws;             // 262144 f16 = 512 KB
  _Float16* VT   = ws + 262144;    // 262144 f16
  _Float16* VT2  = ws + 524288;    // 262144 f16

  prep_kernel<<<512, 1024, 0, stream>>>(h_obs, fw1, fb1, fw2, fb2,
                                        pos_obs, kw1, VT, VT2, AO_h);
  attn_fused<<<NB * NQ / 2, 512, 0, stream>>>(VT, VT2, AO_h, kw1, kb1, kw2, kb2,
                                              log_sigma, pos_obs, pos_query,
                                              ow, ob, vw, vb, out);
}

// Round 3
// 127.670 us; speedup vs baseline: 1.2159x; 1.2159x over previous
//
#include <hip/hip_runtime.h>
#include <math.h>

#define NB 2
#define NO 512
#define NQ 512
#define OUT_DIM 128
#define LPAD 516   // logits row pitch (floats): 16B-aligned, bank-staggered

typedef __attribute__((ext_vector_type(8))) _Float16 half8;  // 4 VGPR
typedef __attribute__((ext_vector_type(4))) _Float16 half4;  // 2 VGPR
typedef __attribute__((ext_vector_type(4))) float f32x4;     // MFMA acc

__device__ __forceinline__ float softplus_f(float x) {
  return x > 0.0f ? x + log1pf(expf(-x)) : log1pf(expf(x));
}
__device__ __forceinline__ half8 splat8(_Float16 v) {
  return (half8){v, v, v, v, v, v, v, v};
}
__device__ __forceinline__ half8 fma8(half8 a, half8 b, half8 c) {
  return __builtin_elementwise_fma(a, b, c);
}
__device__ __forceinline__ half8 max8(half8 a, half8 b) {
  return __builtin_elementwise_max(a, b);
}
// async global->LDS, 16B per lane; dest = lds_base + lane*16 (wave-uniform base)
__device__ __forceinline__ void gll16(const void* g, void* l) {
  __builtin_amdgcn_global_load_lds(
      (const __attribute__((address_space(1))) unsigned int*)g,
      (__attribute__((address_space(3))) unsigned int*)l, 16, 0, 0);
}

// ---------------------------------------------------------------------------
// Prep: fused 2-layer MLP -> VT (f16, head-transposed [b][h][d][o]).
__global__ __launch_bounds__(1024) void prep_kernel(
    const float* __restrict__ h_obs, const float* __restrict__ fw1,
    const float* __restrict__ fb1, const float* __restrict__ fw2,
    const float* __restrict__ fb2, _Float16* __restrict__ VT)
{
  __shared__ float s_red[4][4][256];
  __shared__ float s_hid[4][256];
  const int n  = threadIdx.x & 255;
  const int ks = threadIdx.x >> 8;
  const int r0 = blockIdx.x * 4;
  const int k0 = ks * 64;
  float a0 = 0.f, a1 = 0.f, a2 = 0.f, a3 = 0.f;
  #pragma unroll 8
  for (int kk = 0; kk < 64; ++kk) {
    int k = k0 + kk;
    float w = fw1[k * 256 + n];
    a0 = fmaf(h_obs[(r0 + 0) * 256 + k], w, a0);
    a1 = fmaf(h_obs[(r0 + 1) * 256 + k], w, a1);
    a2 = fmaf(h_obs[(r0 + 2) * 256 + k], w, a2);
    a3 = fmaf(h_obs[(r0 + 3) * 256 + k], w, a3);
  }
  s_red[ks][0][n] = a0; s_red[ks][1][n] = a1;
  s_red[ks][2][n] = a2; s_red[ks][3][n] = a3;
  __syncthreads();
  if (ks == 0) {
    float bb = fb1[n];
    #pragma unroll
    for (int r = 0; r < 4; ++r) {
      float v = s_red[0][r][n] + s_red[1][r][n] + s_red[2][r][n] + s_red[3][r][n] + bb;
      s_hid[r][n] = fmaxf(v, 0.f);
    }
  }
  __syncthreads();
  float c0 = 0.f, c1 = 0.f, c2 = 0.f, c3 = 0.f;
  #pragma unroll 8
  for (int kk = 0; kk < 64; ++kk) {
    int k = k0 + kk;
    float w = fw2[k * 256 + n];
    c0 = fmaf(s_hid[0][k], w, c0);
    c1 = fmaf(s_hid[1][k], w, c1);
    c2 = fmaf(s_hid[2][k], w, c2);
    c3 = fmaf(s_hid[3][k], w, c3);
  }
  __syncthreads();
  s_red[ks][0][n] = c0; s_red[ks][1][n] = c1;
  s_red[ks][2][n] = c2; s_red[ks][3][n] = c3;
  __syncthreads();
  if (ks == 0) {
    float bb = fb2[n];
    float vr[4];
    #pragma unroll
    for (int r = 0; r < 4; ++r)
      vr[r] = s_red[0][r][n] + s_red[1][r][n] + s_red[2][r][n] + s_red[3][r][n] + bb;
    // transpose store: thread n owns column (h,d); 4 consecutive o
    const int h  = n >> 5, d = n & 31;
    const int bb_ = r0 >> 9, o0 = r0 & 511;
    half4 pv;
    #pragma unroll
    for (int r = 0; r < 4; ++r) pv[r] = (_Float16)vr[r];
    *(half4*)(VT + ((size_t)((bb_ * 8 + h) * 32 + d)) * 512 + o0) = pv;
  }
}

// ---------------------------------------------------------------------------
// Fused attention + out_proj. QT=2 per block, 512 threads (8 waves).
// Phase 1: f16 MFMA delta; ao built IN-REGISTER from rank-3 pos projection
//          (no AO global stream). Phase 3: PV / P*V^2 via f16 MFMA with VT
//          async-staged into (dead) logits LDS via global_load_lds, v^2 in
//          register, P consumed as f16 straight from LDS.
__global__ __launch_bounds__(512, 4) void attn_fused(
    const _Float16* __restrict__ VT,     // [b][h][d][o] f16
    const float* __restrict__ kw1,       // (9, 256)
    const float* __restrict__ kb1,       // (256)
    const float* __restrict__ kw2,       // (256, 8)
    const float* __restrict__ kb2,       // (8)
    const float* __restrict__ log_sigma, // (8)
    const float* __restrict__ pos_obs,   // (B*NO, 3)
    const float* __restrict__ pos_query, // (B*NQ, 3)
    const float* __restrict__ ow, const float* __restrict__ obias,
    const float* __restrict__ vw, const float* __restrict__ vbias,
    float* __restrict__ out)
{
  __shared__ __align__(16) float s_logits[2][8 * LPAD];   // 33024 B; phase3: VT stage
  __shared__ __align__(16) _Float16 s_P16[2][8][520];     // 16640 B (P, f16)
  __shared__ half8 s_Bh[512];                             // 8192 B (kw2 f16 frags)
  __shared__ __align__(16) float s_pool[2048];            // 8192 B
  __shared__ __align__(16) float s_po[3][516];            // 6192 B (pos_obs, SoA)
  __shared__ __align__(16) _Float16 s_co[3][264];         // 1584 B (ao coeff table)

  _Float16* s_aq2 = (_Float16*)s_pool;   // [2][256] f16 (phase 1 only)
  float*    s_hv   = s_pool;             // [(q*2+kind)*256+hd] (phase 3/4)
  float*    s_pred = s_pool + 1024;      // [ks][mode][q][128]  (phase 4)

  const int t   = threadIdx.x;
  const int bq0 = blockIdx.x * 2;
  const int b   = bq0 >> 9;

  // ---- prologue -----------------------------------------------------------
  float pqx[2], pqy[2], pqz[2];
  #pragma unroll
  for (int q = 0; q < 2; ++q) {
    pqx[q] = pos_query[(bq0 + q) * 3 + 0];
    pqy[q] = pos_query[(bq0 + q) * 3 + 1];
    pqz[q] = pos_query[(bq0 + q) * 3 + 2];
  }
  // aq[q][j] in f16
  {
    const int q = t >> 8, j = t & 255;
    float c0 = kw1[0 * 256 + j] + kw1[6 * 256 + j];
    float c1 = kw1[1 * 256 + j] + kw1[7 * 256 + j];
    float c2 = kw1[2 * 256 + j] + kw1[8 * 256 + j];
    s_aq2[q * 256 + j] = (_Float16)
        fmaf(pqx[q], c0, fmaf(pqy[q], c1, fmaf(pqz[q], c2, kb1[j])));
  }
  // ao coefficient table (rank-3): co[c][j], f16
  if (t < 256) {
    const int j = t;
    s_co[0][j] = (_Float16)(kw1[3 * 256 + j] - kw1[6 * 256 + j]);
    s_co[1][j] = (_Float16)(kw1[4 * 256 + j] - kw1[7 * 256 + j]);
    s_co[2][j] = (_Float16)(kw1[5 * 256 + j] - kw1[8 * 256 + j]);
  }
  // pos_obs SoA + logits prefill (rbf + kb2) for o = t, both q, all h
  {
    const int o = t;
    const float* p = pos_obs + (size_t)(b * NO + o) * 3;
    float px = p[0], py = p[1], pz = p[2];
    s_po[0][o] = px; s_po[1][o] = py; s_po[2][o] = pz;
    float d2q[2];
    #pragma unroll
    for (int q = 0; q < 2; ++q) {
      float r0 = pqx[q] - px, r1 = pqy[q] - py, r2 = pqz[q] - pz;
      d2q[q] = r0 * r0 + r1 * r1 + r2 * r2;
    }
    #pragma unroll
    for (int h = 0; h < 8; ++h) {
      float sg  = __expf(log_sigma[h]);
      float inv = 1.0f / (sg * sg + 1e-6f);
      float kbv = kb2[h];
      s_logits[0][h * LPAD + o] = __logf(__expf(-d2q[0] * inv) + 1e-8f) + kbv;
      s_logits[1][h * LPAD + o] = __logf(__expf(-d2q[1] * inv) + 1e-8f) + kbv;
    }
  }
  // B fragments: kw2 as f16
  {
    const int kstep = t >> 6, lane = t & 63;
    const int nh = lane & 15;
    const int kb_ = kstep * 32 + ((lane >> 4) & 3) * 8;
    half8 b8;
    #pragma unroll
    for (int i = 0; i < 8; ++i) {
      float v = (nh < 8) ? kw2[(kb_ + i) * 8 + nh] : 0.f;
      b8[i] = (_Float16)v;
    }
    s_Bh[kstep * 64 + lane] = b8;
  }
  __syncthreads();

  // ---- phase 1: f16 MFMA delta; A = relu(aq + pos.co) all in packed f16 ---
  {
    const int wave = t >> 6, lane = t & 63;
    const int quad = lane >> 4, mrow = lane & 15;
    const int tb   = wave * 4;
    _Float16 pxh[4], pyh[4], pzh[4];
    #pragma unroll
    for (int jt = 0; jt < 4; ++jt) {
      const int o = (tb + jt) * 16 + mrow;
      pxh[jt] = (_Float16)s_po[0][o];
      pyh[jt] = (_Float16)s_po[1][o];
      pzh[jt] = (_Float16)s_po[2][o];
    }
    f32x4 C[2][4];
    #pragma unroll
    for (int q = 0; q < 2; ++q)
      #pragma unroll
      for (int jt = 0; jt < 4; ++jt) C[q][jt] = (f32x4){0.f, 0.f, 0.f, 0.f};

    const half8 z8 = {0, 0, 0, 0, 0, 0, 0, 0};
    #pragma unroll
    for (int kstep = 0; kstep < 8; ++kstep) {
      const int koff = kstep * 32 + quad * 8;
      half8 c0 = *(const half8*)&s_co[0][koff];
      half8 c1 = *(const half8*)&s_co[1][koff];
      half8 c2 = *(const half8*)&s_co[2][koff];
      half8 aq0 = *(const half8*)(s_aq2 + koff);
      half8 aq1 = *(const half8*)(s_aq2 + 256 + koff);
      half8 bh  = s_Bh[kstep * 64 + lane];
      #pragma unroll
      for (int jt = 0; jt < 4; ++jt) {
        half8 ao = fma8(splat8(pxh[jt]), c0,
                   fma8(splat8(pyh[jt]), c1, splat8(pzh[jt]) * c2));
        half8 a0 = max8(aq0 + ao, z8);
        half8 a1 = max8(aq1 + ao, z8);
        C[0][jt] = __builtin_amdgcn_mfma_f32_16x16x32_f16(a0, bh, C[0][jt], 0, 0, 0);
        C[1][jt] = __builtin_amdgcn_mfma_f32_16x16x32_f16(a1, bh, C[1][jt], 0, 0, 0);
      }
    }
    // epilogue: D[n=h=lane&15][m=quad*4+r]; add delta into prefilled logits
    const int hh = lane & 15;
    if (hh < 8) {
      #pragma unroll
      for (int q = 0; q < 2; ++q)
        #pragma unroll
        for (int jt = 0; jt < 4; ++jt) {
          const int ob2 = (tb + jt) * 16 + quad * 4;
          #pragma unroll
          for (int r = 0; r < 4; ++r)
            s_logits[q][hh * LPAD + ob2 + r] += C[q][jt][r];
        }
    }
  }
  __syncthreads();

  // ---- phase 2+3: per-wave (=head) softmax -> P16; PV / PV^2 via MFMA -----
  {
    const int h = t >> 6, lane = t & 63;
    float invq[2];
    #pragma unroll
    for (int q = 0; q < 2; ++q) {
      float* pl = &s_logits[q][h * LPAD];
      float l8[8];
      float m = -1e30f;
      #pragma unroll
      for (int k = 0; k < 8; ++k) {
        l8[k] = pl[k * 64 + lane];
        m = fmaxf(m, l8[k]);
      }
      #pragma unroll
      for (int off = 32; off >= 1; off >>= 1) m = fmaxf(m, __shfl_xor(m, off, 64));
      float s = 0.f;
      #pragma unroll
      for (int k = 0; k < 8; ++k) {
        float p = __expf(l8[k] - m);
        s += p;
        s_P16[q][h][k * 64 + lane] = (_Float16)p;
      }
      #pragma unroll
      for (int off = 32; off >= 1; off >>= 1) s += __shfl_xor(s, off, 64);
      invq[q] = 1.0f / s;
    }
    __syncthreads();   // logits fully read chip-wide; region becomes VT stage

    // ---- phase 3 ----------------------------------------------------------
    const int kg = lane >> 4, dl = lane & 15;
    char* stg = (char*)s_logits + h * 4096;          // 4 x 1KB slice buffers
    const _Float16* vt = VT + ((size_t)(b * 8 + h) << 14);   // head base (32x512)
    const _Float16* vsrc = vt + (lane >> 1) * 512 + (lane & 1) * 8;
    // slice j covers o = j*16..+16, layout [32 d][16 o] (row = 32 B)
    #define STAGE(j) gll16(vsrc + (j) * 16, stg + ((j) & 3) * 1024)
    STAGE(0); STAGE(1); STAGE(2); STAGE(3);

    const _Float16* pB = &s_P16[lane & 1][h][0];
    f32x4 Cm0 = {0.f, 0.f, 0.f, 0.f}, Cm1 = Cm0, Cv0 = Cm0, Cv1 = Cm0;
    #pragma unroll
    for (int ks = 0; ks < 16; ++ks) {
      if (ks < 15) asm volatile("s_waitcnt vmcnt(2)" ::: "memory");
      else         asm volatile("s_waitcnt vmcnt(0)" ::: "memory");
      const char* bufc = stg + ((2 * ks + (kg >> 1)) & 3) * 1024
                       + dl * 32 + (kg & 1) * 16;
      half8 am0 = *(const half8*)(bufc);
      half8 am1 = *(const half8*)(bufc + 512);       // d + 16
      half8 pb  = *(const half8*)(pB + ks * 32 + kg * 8);
      half8 av0 = am0 * am0;
      half8 av1 = am1 * am1;
      Cm0 = __builtin_amdgcn_mfma_f32_16x16x32_f16(am0, pb, Cm0, 0, 0, 0);
      Cm1 = __builtin_amdgcn_mfma_f32_16x16x32_f16(am1, pb, Cm1, 0, 0, 0);
      Cv0 = __builtin_amdgcn_mfma_f32_16x16x32_f16(av0, pb, Cv0, 0, 0, 0);
      Cv1 = __builtin_amdgcn_mfma_f32_16x16x32_f16(av1, pb, Cv1, 0, 0, 0);
      if (ks < 14) {
        // ds_reads above are complete (MFMA consumed them); safe to overwrite
        asm volatile("s_waitcnt lgkmcnt(0)" ::: "memory");
        STAGE(2 * ks + 4); STAGE(2 * ks + 5);
      }
    }
    #undef STAGE
    // epilogue: C row = kg*4+r (=d_local), col = nq (=q). Normalize + var.
    const int nq = lane & 15;
    if (nq < 2) {
      const float iv = invq[nq];
      const int dbase = h * 32 + kg * 4;
      f32x4 m0, v0, m1, v1;
      #pragma unroll
      for (int r = 0; r < 4; ++r) {
        float a = Cm0[r] * iv;
        m0[r] = a; v0[r] = fmaxf(Cv0[r] * iv - a * a, 0.f);
        float c = Cm1[r] * iv;
        m1[r] = c; v1[r] = fmaxf(Cv1[r] * iv - c * c, 0.f);
      }
      *(f32x4*)(s_hv + (nq * 2 + 0) * 256 + dbase)      = m0;
      *(f32x4*)(s_hv + (nq * 2 + 1) * 256 + dbase)      = v0;
      *(f32x4*)(s_hv + (nq * 2 + 0) * 256 + dbase + 16) = m1;
      *(f32x4*)(s_hv + (nq * 2 + 1) * 256 + dbase + 16) = v1;
    }
  }
  __syncthreads();

  // ---- phase 4: out_proj, k-split 2, W read once per (mode,ks) ------------
  {
    const int ks = t >> 8, mode = (t >> 7) & 1, n = t & 127;
    const float* W  = mode ? vw : ow;
    const float* X0 = s_hv + mode * 256;        // q0
    const float* X1 = s_hv + (2 + mode) * 256;  // q1
    float a0 = 0.f, a1 = 0.f;
    const int k0 = ks * 128;
    #pragma unroll 4
    for (int k = k0; k < k0 + 128; k += 4) {
      float4 x0 = *(const float4*)&X0[k];
      float4 x1 = *(const float4*)&X1[k];
      float w0 = W[(k + 0) * 128 + n];
      float w1 = W[(k + 1) * 128 + n];
      float w2 = W[(k + 2) * 128 + n];
      float w3 = W[(k + 3) * 128 + n];
      a0 = fmaf(x0.x, w0, a0); a1 = fmaf(x1.x, w0, a1);
      a0 = fmaf(x0.y, w1, a0); a1 = fmaf(x1.y, w1, a1);
      a0 = fmaf(x0.z, w2, a0); a1 = fmaf(x1.z, w2, a1);
      a0 = fmaf(x0.w, w3, a0); a1 = fmaf(x1.w, w3, a1);
    }
    s_pred[((ks * 2 + mode) * 2 + 0) * 128 + n] = a0;   // disjoint from s_hv
    s_pred[((ks * 2 + mode) * 2 + 1) * 128 + n] = a1;
  }
  __syncthreads();
  {
    const int q = t >> 8, mode = (t >> 7) & 1, n = t & 127;
    float v = s_pred[((0 * 2 + mode) * 2 + q) * 128 + n]
            + s_pred[((1 * 2 + mode) * 2 + q) * 128 + n]
            + (mode ? vbias[n] : obias[n]);
    if (mode) v = softplus_f(v);
    out[(size_t)mode * (NB * NQ * OUT_DIM) + (size_t)(bq0 + q) * OUT_DIM + n] = v;
  }
}

// ---------------------------------------------------------------------------
extern "C" void kernel_launch(void* const* d_in, const int* in_sizes, int n_in,
                              void* d_out, int out_size, void* d_ws, size_t ws_size,
                              hipStream_t stream)
{
  const float* h_obs     = (const float*)d_in[0];
  const float* pos_obs   = (const float*)d_in[1];
  const float* pos_query = (const float*)d_in[2];
  const float* fw1       = (const float*)d_in[3];
  const float* fb1       = (const float*)d_in[4];
  const float* fw2       = (const float*)d_in[5];
  const float* fb2       = (const float*)d_in[6];
  const float* log_sigma = (const float*)d_in[7];
  const float* kw1       = (const float*)d_in[8];
  const float* kb1       = (const float*)d_in[9];
  const float* kw2       = (const float*)d_in[10];
  const float* kb2       = (const float*)d_in[11];
  const float* ow        = (const float*)d_in[12];
  const float* ob        = (const float*)d_in[13];
  const float* vw        = (const float*)d_in[14];
  const float* vb        = (const float*)d_in[15];

  float* out = (float*)d_out;
  _Float16* VT = (_Float16*)d_ws;   // 262144 f16 = 512 KB

  prep_kernel<<<256, 1024, 0, stream>>>(h_obs, fw1, fb1, fw2, fb2, VT);
  attn_fused<<<NB * NQ / 2, 512, 0, stream>>>(VT, kw1, kb1, kw2, kb2,
                                              log_sigma, pos_obs, pos_query,
                                              ow, ob, vw, vb, out);
}

// Round 4
// 125.291 us; speedup vs baseline: 1.2390x; 1.0190x over previous
//
#include <hip/hip_runtime.h>
#include <math.h>

#define NB 2
#define NO 512
#define NQ 512
#define OUT_DIM 128
#define LPAD 516   // logits row pitch (floats): row = 2064 B (16B-mult), bank-staggered

typedef __attribute__((ext_vector_type(8))) _Float16 half8;  // 4 VGPR
typedef __attribute__((ext_vector_type(4))) _Float16 half4;  // 2 VGPR
typedef __attribute__((ext_vector_type(4))) float f32x4;     // MFMA acc

__device__ __forceinline__ float softplus_f(float x) {
  return x > 0.0f ? x + log1pf(expf(-x)) : log1pf(expf(x));
}
__device__ __forceinline__ half8 splat8(_Float16 v) {
  return (half8){v, v, v, v, v, v, v, v};
}
__device__ __forceinline__ half8 fma8(half8 a, half8 b, half8 c) {
  return __builtin_elementwise_fma(a, b, c);
}
__device__ __forceinline__ half8 max8(half8 a, half8 b) {
  return __builtin_elementwise_max(a, b);
}
// async global->LDS, 16B per lane; dest = lds_base + lane*16 (wave-uniform base)
__device__ __forceinline__ void gll16(const void* g, void* l) {
  __builtin_amdgcn_global_load_lds(
      (const __attribute__((address_space(1))) unsigned int*)g,
      (__attribute__((address_space(3))) unsigned int*)l, 16, 0, 0);
}

// ---------------------------------------------------------------------------
// Prep: fused 2-layer MLP -> VT (f16, head-transposed [b][h][d][o]).
__global__ __launch_bounds__(1024) void prep_kernel(
    const float* __restrict__ h_obs, const float* __restrict__ fw1,
    const float* __restrict__ fb1, const float* __restrict__ fw2,
    const float* __restrict__ fb2, _Float16* __restrict__ VT)
{
  __shared__ float s_red[4][4][256];
  __shared__ float s_hid[4][256];
  const int n  = threadIdx.x & 255;
  const int ks = threadIdx.x >> 8;
  const int r0 = blockIdx.x * 4;
  const int k0 = ks * 64;
  float a0 = 0.f, a1 = 0.f, a2 = 0.f, a3 = 0.f;
  #pragma unroll 8
  for (int kk = 0; kk < 64; ++kk) {
    int k = k0 + kk;
    float w = fw1[k * 256 + n];
    a0 = fmaf(h_obs[(r0 + 0) * 256 + k], w, a0);
    a1 = fmaf(h_obs[(r0 + 1) * 256 + k], w, a1);
    a2 = fmaf(h_obs[(r0 + 2) * 256 + k], w, a2);
    a3 = fmaf(h_obs[(r0 + 3) * 256 + k], w, a3);
  }
  s_red[ks][0][n] = a0; s_red[ks][1][n] = a1;
  s_red[ks][2][n] = a2; s_red[ks][3][n] = a3;
  __syncthreads();
  if (ks == 0) {
    float bb = fb1[n];
    #pragma unroll
    for (int r = 0; r < 4; ++r) {
      float v = s_red[0][r][n] + s_red[1][r][n] + s_red[2][r][n] + s_red[3][r][n] + bb;
      s_hid[r][n] = fmaxf(v, 0.f);
    }
  }
  __syncthreads();
  float c0 = 0.f, c1 = 0.f, c2 = 0.f, c3 = 0.f;
  #pragma unroll 8
  for (int kk = 0; kk < 64; ++kk) {
    int k = k0 + kk;
    float w = fw2[k * 256 + n];
    c0 = fmaf(s_hid[0][k], w, c0);
    c1 = fmaf(s_hid[1][k], w, c1);
    c2 = fmaf(s_hid[2][k], w, c2);
    c3 = fmaf(s_hid[3][k], w, c3);
  }
  __syncthreads();
  s_red[ks][0][n] = c0; s_red[ks][1][n] = c1;
  s_red[ks][2][n] = c2; s_red[ks][3][n] = c3;
  __syncthreads();
  if (ks == 0) {
    float bb = fb2[n];
    float vr[4];
    #pragma unroll
    for (int r = 0; r < 4; ++r)
      vr[r] = s_red[0][r][n] + s_red[1][r][n] + s_red[2][r][n] + s_red[3][r][n] + bb;
    // transpose store: thread n owns column (h,d); 4 consecutive o
    const int h  = n >> 5, d = n & 31;
    const int bb_ = r0 >> 9, o0 = r0 & 511;
    half4 pv;
    #pragma unroll
    for (int r = 0; r < 4; ++r) pv[r] = (_Float16)vr[r];
    *(half4*)(VT + ((size_t)((bb_ * 8 + h) * 32 + d)) * 512 + o0) = pv;
  }
}

// ---------------------------------------------------------------------------
// Fused attention + out_proj. QT=2 per block, 512 threads (8 waves).
// Phase 1: f16 MFMA delta; ao built in-register (rank-3 pos projection).
// Phase 2+3: per-wave (=head), NO barrier between softmax and PV — each wave
//   stages VT slices into ITS OWN dead LDS (its s_Bh slot + its two logits
//   rows), so waves drift independently and hide each other's latency.
__global__ __launch_bounds__(512, 4) void attn_fused(
    const _Float16* __restrict__ VT,     // [b][h][d][o] f16
    const float* __restrict__ kw1,       // (9, 256)
    const float* __restrict__ kb1,       // (256)
    const float* __restrict__ kw2,       // (256, 8)
    const float* __restrict__ kb2,       // (8)
    const float* __restrict__ log_sigma, // (8)
    const float* __restrict__ pos_obs,   // (B*NO, 3)
    const float* __restrict__ pos_query, // (B*NQ, 3)
    const float* __restrict__ ow, const float* __restrict__ obias,
    const float* __restrict__ vw, const float* __restrict__ vbias,
    float* __restrict__ out)
{
  __shared__ __align__(16) float s_logits[2][8 * LPAD];   // 33024 B; ph3: per-wave VT stage
  __shared__ __align__(16) _Float16 s_P16[2][8][520];     // 16640 B (P, f16)
  __shared__ half8 s_Bh[512];                             // 8192 B (kw2 frags; ph3: slice-0)
  __shared__ __align__(16) float s_pool[2048];            // 8192 B
  __shared__ __align__(16) float s_po[3][516];            // 6192 B (pos_obs, SoA)
  __shared__ __align__(16) _Float16 s_co[3][264];         // 1584 B (ao coeff table)

  _Float16* s_aq2 = (_Float16*)s_pool;   // [2][256] f16 (phase 1 only)
  float*    s_hv   = s_pool;             // [(q*2+kind)*256+hd] (phase 3/4)
  float*    s_pred = s_pool + 1024;      // [ks][mode][q][128]  (phase 4)

  const int t   = threadIdx.x;
  const int bq0 = blockIdx.x * 2;
  const int b   = bq0 >> 9;

  // ---- prologue -----------------------------------------------------------
  float pqx[2], pqy[2], pqz[2];
  #pragma unroll
  for (int q = 0; q < 2; ++q) {
    pqx[q] = pos_query[(bq0 + q) * 3 + 0];
    pqy[q] = pos_query[(bq0 + q) * 3 + 1];
    pqz[q] = pos_query[(bq0 + q) * 3 + 2];
  }
  // aq[q][j] in f16
  {
    const int q = t >> 8, j = t & 255;
    float c0 = kw1[0 * 256 + j] + kw1[6 * 256 + j];
    float c1 = kw1[1 * 256 + j] + kw1[7 * 256 + j];
    float c2 = kw1[2 * 256 + j] + kw1[8 * 256 + j];
    s_aq2[q * 256 + j] = (_Float16)
        fmaf(pqx[q], c0, fmaf(pqy[q], c1, fmaf(pqz[q], c2, kb1[j])));
  }
  // ao coefficient table (rank-3): co[c][j], f16
  if (t < 256) {
    const int j = t;
    s_co[0][j] = (_Float16)(kw1[3 * 256 + j] - kw1[6 * 256 + j]);
    s_co[1][j] = (_Float16)(kw1[4 * 256 + j] - kw1[7 * 256 + j]);
    s_co[2][j] = (_Float16)(kw1[5 * 256 + j] - kw1[8 * 256 + j]);
  }
  // pos_obs SoA + logits prefill (rbf + kb2) for o = t, both q, all h.
  // log(exp(t)+1e-8) ~= max(t, log(1e-8)): row-max is always > -3*inv, so the
  // clamp region carries softmax weight < e^-15 of max -> error invisible.
  {
    const int o = t;
    const float* p = pos_obs + (size_t)(b * NO + o) * 3;
    float px = p[0], py = p[1], pz = p[2];
    s_po[0][o] = px; s_po[1][o] = py; s_po[2][o] = pz;
    float d2q[2];
    #pragma unroll
    for (int q = 0; q < 2; ++q) {
      float r0 = pqx[q] - px, r1 = pqy[q] - py, r2 = pqz[q] - pz;
      d2q[q] = r0 * r0 + r1 * r1 + r2 * r2;
    }
    #pragma unroll
    for (int h = 0; h < 8; ++h) {
      float sg  = __expf(log_sigma[h]);
      float inv = 1.0f / (sg * sg + 1e-6f);
      float kbv = kb2[h];
      s_logits[0][h * LPAD + o] = fmaxf(-d2q[0] * inv, -18.420681f) + kbv;
      s_logits[1][h * LPAD + o] = fmaxf(-d2q[1] * inv, -18.420681f) + kbv;
    }
  }
  // B fragments: kw2 as f16
  {
    const int kstep = t >> 6, lane = t & 63;
    const int nh = lane & 15;
    const int kb_ = kstep * 32 + ((lane >> 4) & 3) * 8;
    half8 b8;
    #pragma unroll
    for (int i = 0; i < 8; ++i) {
      float v = (nh < 8) ? kw2[(kb_ + i) * 8 + nh] : 0.f;
      b8[i] = (_Float16)v;
    }
    s_Bh[kstep * 64 + lane] = b8;
  }
  __syncthreads();

  // ---- phase 1: f16 MFMA delta; A = relu(aq + pos.co) all in packed f16 ---
  {
    const int wave = t >> 6, lane = t & 63;
    const int quad = lane >> 4, mrow = lane & 15;
    const int tb   = wave * 4;
    _Float16 pxh[4], pyh[4], pzh[4];
    #pragma unroll
    for (int jt = 0; jt < 4; ++jt) {
      const int o = (tb + jt) * 16 + mrow;
      pxh[jt] = (_Float16)s_po[0][o];
      pyh[jt] = (_Float16)s_po[1][o];
      pzh[jt] = (_Float16)s_po[2][o];
    }
    f32x4 C[2][4];
    #pragma unroll
    for (int q = 0; q < 2; ++q)
      #pragma unroll
      for (int jt = 0; jt < 4; ++jt) C[q][jt] = (f32x4){0.f, 0.f, 0.f, 0.f};

    const half8 z8 = {0, 0, 0, 0, 0, 0, 0, 0};
    #pragma unroll
    for (int kstep = 0; kstep < 8; ++kstep) {
      const int koff = kstep * 32 + quad * 8;
      half8 c0 = *(const half8*)&s_co[0][koff];
      half8 c1 = *(const half8*)&s_co[1][koff];
      half8 c2 = *(const half8*)&s_co[2][koff];
      half8 aq0 = *(const half8*)(s_aq2 + koff);
      half8 aq1 = *(const half8*)(s_aq2 + 256 + koff);
      half8 bh  = s_Bh[kstep * 64 + lane];
      #pragma unroll
      for (int jt = 0; jt < 4; ++jt) {
        half8 ao = fma8(splat8(pxh[jt]), c0,
                   fma8(splat8(pyh[jt]), c1, splat8(pzh[jt]) * c2));
        half8 a0 = max8(aq0 + ao, z8);
        half8 a1 = max8(aq1 + ao, z8);
        C[0][jt] = __builtin_amdgcn_mfma_f32_16x16x32_f16(a0, bh, C[0][jt], 0, 0, 0);
        C[1][jt] = __builtin_amdgcn_mfma_f32_16x16x32_f16(a1, bh, C[1][jt], 0, 0, 0);
      }
    }
    // epilogue: D[n=h=lane&15][m=quad*4+r]; add delta into prefilled logits
    const int hh = lane & 15;
    if (hh < 8) {
      #pragma unroll
      for (int q = 0; q < 2; ++q)
        #pragma unroll
        for (int jt = 0; jt < 4; ++jt) {
          const int ob2 = (tb + jt) * 16 + quad * 4;
          #pragma unroll
          for (int r = 0; r < 4; ++r)
            s_logits[q][hh * LPAD + ob2 + r] += C[q][jt][r];
        }
    }
  }
  __syncthreads();   // last block-wide barrier before phase 4

  // ---- phase 2+3: per-wave (=head), barrier-free --------------------------
  {
    const int h = t >> 6, lane = t & 63;
    const int kg = lane >> 4, dl = lane & 15;
    // wave-private staging buffers (all dead for everyone else):
    //   buf0 = own s_Bh slot; buf1/buf3 = own q0 logits row; buf2 = own q1 row
    char* stg0 = (char*)s_Bh + h * 1024;
    char* b1   = (char*)&s_logits[0][h * LPAD];
    char* b3   = b1 + 1024;
    char* b2   = (char*)&s_logits[1][h * LPAD];
    const _Float16* vsrc = VT + ((size_t)(b * 8 + h) << 14)
                         + (lane >> 1) * 512 + (lane & 1) * 8;
    gll16(vsrc, stg0);                 // slice 0: hides under softmax

    // softmax, q0/q1 interleaved (2 independent shfl chains -> ILP)
    float invq0, invq1;
    {
      const float* pl0 = &s_logits[0][h * LPAD];
      const float* pl1 = &s_logits[1][h * LPAD];
      float l0[8], l1[8];
      float m0 = -1e30f, m1 = -1e30f;
      #pragma unroll
      for (int k = 0; k < 8; ++k) {
        l0[k] = pl0[k * 64 + lane];
        l1[k] = pl1[k * 64 + lane];
        m0 = fmaxf(m0, l0[k]);
        m1 = fmaxf(m1, l1[k]);
      }
      #pragma unroll
      for (int off = 32; off >= 1; off >>= 1) {
        m0 = fmaxf(m0, __shfl_xor(m0, off, 64));
        m1 = fmaxf(m1, __shfl_xor(m1, off, 64));
      }
      float s0 = 0.f, s1 = 0.f;
      _Float16* pp0 = &s_P16[0][h][0];
      _Float16* pp1 = &s_P16[1][h][0];
      #pragma unroll
      for (int k = 0; k < 8; ++k) {
        float p0 = __expf(l0[k] - m0);
        float p1 = __expf(l1[k] - m1);
        s0 += p0; s1 += p1;
        pp0[k * 64 + lane] = (_Float16)p0;
        pp1[k * 64 + lane] = (_Float16)p1;
      }
      #pragma unroll
      for (int off = 32; off >= 1; off >>= 1) {
        s0 += __shfl_xor(s0, off, 64);
        s1 += __shfl_xor(s1, off, 64);
      }
      invq0 = 1.0f / s0; invq1 = 1.0f / s1;
    }
    // own logits rows now fully read -> become staging buffers
    gll16(vsrc + 16, b1);              // slice 1
    gll16(vsrc + 32, b2);              // slice 2
    gll16(vsrc + 48, b3);              // slice 3

    const char* pE = ((kg & 2) ? b1 : stg0) + dl * 32 + (kg & 1) * 16;
    const char* pO = ((kg & 2) ? b3 : b2)   + dl * 32 + (kg & 1) * 16;
    const _Float16* pB = &s_P16[lane & 1][h][0];
    f32x4 Cm0 = {0.f, 0.f, 0.f, 0.f}, Cm1 = Cm0, Cv0 = Cm0, Cv1 = Cm0;
    #pragma unroll
    for (int kp = 0; kp < 8; ++kp) {
      // even K-step: slices 4kp, 4kp+1 (buf0/buf1)
      asm volatile("s_waitcnt vmcnt(2)" ::: "memory");
      {
        half8 am0 = *(const half8*)(pE);
        half8 am1 = *(const half8*)(pE + 512);       // d + 16
        half8 pb  = *(const half8*)(pB + (2 * kp) * 32 + kg * 8);
        half8 av0 = am0 * am0;
        half8 av1 = am1 * am1;
        __builtin_amdgcn_s_setprio(1);
        Cm0 = __builtin_amdgcn_mfma_f32_16x16x32_f16(am0, pb, Cm0, 0, 0, 0);
        Cm1 = __builtin_amdgcn_mfma_f32_16x16x32_f16(am1, pb, Cm1, 0, 0, 0);
        Cv0 = __builtin_amdgcn_mfma_f32_16x16x32_f16(av0, pb, Cv0, 0, 0, 0);
        Cv1 = __builtin_amdgcn_mfma_f32_16x16x32_f16(av1, pb, Cv1, 0, 0, 0);
        __builtin_amdgcn_s_setprio(0);
      }
      if (kp < 7) {
        asm volatile("s_waitcnt lgkmcnt(0)" ::: "memory");  // reads done; safe to overwrite
        gll16(vsrc + (4 * kp + 4) * 16, stg0);
        gll16(vsrc + (4 * kp + 5) * 16, b1);
      }
      // odd K-step: slices 4kp+2, 4kp+3 (buf2/buf3)
      if (kp < 7) asm volatile("s_waitcnt vmcnt(2)" ::: "memory");
      else        asm volatile("s_waitcnt vmcnt(0)" ::: "memory");
      {
        half8 am0 = *(const half8*)(pO);
        half8 am1 = *(const half8*)(pO + 512);
        half8 pb  = *(const half8*)(pB + (2 * kp + 1) * 32 + kg * 8);
        half8 av0 = am0 * am0;
        half8 av1 = am1 * am1;
        __builtin_amdgcn_s_setprio(1);
        Cm0 = __builtin_amdgcn_mfma_f32_16x16x32_f16(am0, pb, Cm0, 0, 0, 0);
        Cm1 = __builtin_amdgcn_mfma_f32_16x16x32_f16(am1, pb, Cm1, 0, 0, 0);
        Cv0 = __builtin_amdgcn_mfma_f32_16x16x32_f16(av0, pb, Cv0, 0, 0, 0);
        Cv1 = __builtin_amdgcn_mfma_f32_16x16x32_f16(av1, pb, Cv1, 0, 0, 0);
        __builtin_amdgcn_s_setprio(0);
      }
      if (kp < 7) {
        asm volatile("s_waitcnt lgkmcnt(0)" ::: "memory");
        gll16(vsrc + (4 * kp + 6) * 16, b2);
        gll16(vsrc + (4 * kp + 7) * 16, b3);
      }
    }
    // epilogue: C row = kg*4+r (=d_local), col = nq (=q). Normalize + var.
    const int nq = lane & 15;
    if (nq < 2) {
      const float iv = nq ? invq1 : invq0;
      const int dbase = h * 32 + kg * 4;
      f32x4 m0, v0, m1, v1;
      #pragma unroll
      for (int r = 0; r < 4; ++r) {
        float a = Cm0[r] * iv;
        m0[r] = a; v0[r] = fmaxf(Cv0[r] * iv - a * a, 0.f);
        float c = Cm1[r] * iv;
        m1[r] = c; v1[r] = fmaxf(Cv1[r] * iv - c * c, 0.f);
      }
      *(f32x4*)(s_hv + (nq * 2 + 0) * 256 + dbase)      = m0;
      *(f32x4*)(s_hv + (nq * 2 + 1) * 256 + dbase)      = v0;
      *(f32x4*)(s_hv + (nq * 2 + 0) * 256 + dbase + 16) = m1;
      *(f32x4*)(s_hv + (nq * 2 + 1) * 256 + dbase + 16) = v1;
    }
  }
  __syncthreads();

  // ---- phase 4: out_proj, k-split 2, W read once per (mode,ks) ------------
  {
    const int ks = t >> 8, mode = (t >> 7) & 1, n = t & 127;
    const float* W  = mode ? vw : ow;
    const float* X0 = s_hv + mode * 256;        // q0
    const float* X1 = s_hv + (2 + mode) * 256;  // q1
    float a0 = 0.f, a1 = 0.f;
    const int k0 = ks * 128;
    #pragma unroll 4
    for (int k = k0; k < k0 + 128; k += 4) {
      float4 x0 = *(const float4*)&X0[k];
      float4 x1 = *(const float4*)&X1[k];
      float w0 = W[(k + 0) * 128 + n];
      float w1 = W[(k + 1) * 128 + n];
      float w2 = W[(k + 2) * 128 + n];
      float w3 = W[(k + 3) * 128 + n];
      a0 = fmaf(x0.x, w0, a0); a1 = fmaf(x1.x, w0, a1);
      a0 = fmaf(x0.y, w1, a0); a1 = fmaf(x1.y, w1, a1);
      a0 = fmaf(x0.z, w2, a0); a1 = fmaf(x1.z, w2, a1);
      a0 = fmaf(x0.w, w3, a0); a1 = fmaf(x1.w, w3, a1);
    }
    s_pred[((ks * 2 + mode) * 2 + 0) * 128 + n] = a0;   // disjoint from s_hv
    s_pred[((ks * 2 + mode) * 2 + 1) * 128 + n] = a1;
  }
  __syncthreads();
  {
    const int q = t >> 8, mode = (t >> 7) & 1, n = t & 127;
    float v = s_pred[((0 * 2 + mode) * 2 + q) * 128 + n]
            + s_pred[((1 * 2 + mode) * 2 + q) * 128 + n]
            + (mode ? vbias[n] : obias[n]);
    if (mode) v = softplus_f(v);
    out[(size_t)mode * (NB * NQ * OUT_DIM) + (size_t)(bq0 + q) * OUT_DIM + n] = v;
  }
}

// ---------------------------------------------------------------------------
extern "C" void kernel_launch(void* const* d_in, const int* in_sizes, int n_in,
                              void* d_out, int out_size, void* d_ws, size_t ws_size,
                              hipStream_t stream)
{
  const float* h_obs     = (const float*)d_in[0];
  const float* pos_obs   = (const float*)d_in[1];
  const float* pos_query = (const float*)d_in[2];
  const float* fw1       = (const float*)d_in[3];
  const float* fb1       = (const float*)d_in[4];
  const float* fw2       = (const float*)d_in[5];
  const float* fb2       = (const float*)d_in[6];
  const float* log_sigma = (const float*)d_in[7];
  const float* kw1       = (const float*)d_in[8];
  const float* kb1       = (const float*)d_in[9];
  const float* kw2       = (const float*)d_in[10];
  const float* kb2       = (const float*)d_in[11];
  const float* ow        = (const float*)d_in[12];
  const float* ob        = (const float*)d_in[13];
  const float* vw        = (const float*)d_in[14];
  const float* vb        = (const float*)d_in[15];

  float* out = (float*)d_out;
  _Float16* VT = (_Float16*)d_ws;   // 262144 f16 = 512 KB

  prep_kernel<<<256, 1024, 0, stream>>>(h_obs, fw1, fb1, fw2, fb2, VT);
  attn_fused<<<NB * NQ / 2, 512, 0, stream>>>(VT, kw1, kb1, kw2, kb2,
                                              log_sigma, pos_obs, pos_query,
                                              ow, ob, vw, vb, out);
}